// Round 1
// baseline (632.536 us; speedup 1.0000x reference)
//
#include <hip/hip_runtime.h>

// Joiner: R=32000 rows, K=512, OV=1999, V=2000.
// out  = [blank | enc@W_ev^T + b_ev + vdp]  (R x 2000)
// vdp  = log_softmax(biasnorm(vocab_dec)@W_dv^T + b_dv)  (R x 1999)

#define R_TOTAL 32000
#define OV 1999

typedef __attribute__((ext_vector_type(8))) short bh8;
typedef __attribute__((ext_vector_type(4))) float fx4;

__device__ __forceinline__ unsigned short f2bf(float f) {
  union { float f; unsigned u; } v; v.f = f;
  unsigned r = v.u + 0x7fffu + ((v.u >> 16) & 1u);
  return (unsigned short)(r >> 16);
}
__device__ __forceinline__ float bf2f(unsigned short h) {
  union { unsigned u; float f; } v; v.u = ((unsigned)h) << 16;
  return v.f;
}
__device__ __forceinline__ void gload_lds16(const void* g, void* l) {
  __builtin_amdgcn_global_load_lds(
      (__attribute__((address_space(1))) void*)g,
      (__attribute__((address_space(3))) void*)l, 16, 0, 0);
}

// ---- weight fp32 -> bf16, with optional zero row padding (cols=512) ----
__global__ void wconv_kernel(const float* __restrict__ src, unsigned short* __restrict__ dst,
                             int src_rows, int dst_rows) {
  long long n = (long long)dst_rows * 512;
  for (long long i = (long long)blockIdx.x * blockDim.x + threadIdx.x; i < n;
       i += (long long)gridDim.x * blockDim.x) {
    int row = (int)(i >> 9);
    dst[i] = (row < src_rows) ? f2bf(src[i]) : (unsigned short)0;
  }
}

// ---- GEMM (128 rows x full N=512) + BiasNorm epilogue ----
// MODE 0: store biasnorm result as bf16 to enc_b
// MODE 1: compute biasnorm(bdec), then blank = relu(enc+bdec).W_blank + b_blank -> out[r*2000]
template<int MODE>
__global__ __launch_bounds__(512, 2)
void proj_norm_kernel(const float* __restrict__ X,
                      const unsigned short* __restrict__ Wb,
                      const float* __restrict__ b_lin,
                      const float* __restrict__ bn_bias,
                      const float* __restrict__ log_scale,
                      unsigned short* __restrict__ enc_b,
                      const float* __restrict__ W_blank,
                      const float* __restrict__ b_blank,
                      float* __restrict__ outp)
{
  __shared__ unsigned short As[128 * 64];   // 16 KB, swizzled
  __shared__ unsigned short Bs[512 * 64];   // 64 KB, swizzled
  __shared__ float red[4][128];
  __shared__ float scale_s[128];

  const int tid = threadIdx.x;
  const int l  = tid & 63;
  const int lq = l >> 4;
  const int lr = l & 15;
  const int w  = tid >> 6;      // 0..7
  const int wr = w >> 2;        // 0..1  (64-row slab)
  const int wc = w & 3;         // 0..3  (128-col slab)
  const int rowBase = blockIdx.x * 128;

  char* AsB = (char*)As;
  char* BsB = (char*)Bs;

  fx4 acc[4][8];
#pragma unroll
  for (int m = 0; m < 4; ++m)
#pragma unroll
    for (int n = 0; n < 8; ++n)
#pragma unroll
      for (int r = 0; r < 4; ++r) acc[m][n][r] = 0.f;

  for (int kt = 0; kt < 8; ++kt) {
    // stage A: fp32 -> bf16, reg-staged, XOR-swizzled LDS writes
#pragma unroll
    for (int p = 0; p < 4; ++p) {
      int g = tid + p * 512;
      int row = g >> 4;
      int c4  = g & 15;
      const float4 v = *(const float4*)(X + (long long)(rowBase + row) * 512 + kt * 64 + c4 * 4);
      ushort4 h;
      h.x = f2bf(v.x); h.y = f2bf(v.y); h.z = f2bf(v.z); h.w = f2bf(v.w);
      *(ushort4*)(AsB + row * 128 + ((c4 * 8) ^ ((row & 7) << 4))) = h;
    }
    // stage B: bf16 weights, global_load_lds (linear dest, pre-swizzled source)
#pragma unroll
    for (int p = 0; p < 8; ++p) {
      int gb = (w * 8 + p) * 64;
      int g = gb + l;
      int row = g >> 3;
      int c8 = (g & 7) ^ (row & 7);
      gload_lds16(Wb + (long long)row * 512 + kt * 64 + c8 * 8, BsB + gb * 16);
    }
    __syncthreads();

#pragma unroll
    for (int kk = 0; kk < 2; ++kk) {
      const int kb = (kk * 32 + lq * 8) * 2;
      bh8 a[4];
#pragma unroll
      for (int m = 0; m < 4; ++m) {
        int row = wr * 64 + m * 16 + lr;
        a[m] = *(const bh8*)(AsB + row * 128 + (kb ^ ((row & 7) << 4)));
      }
#pragma unroll
      for (int n = 0; n < 8; ++n) {
        int brow = wc * 128 + n * 16 + lr;
        bh8 bfr = *(const bh8*)(BsB + brow * 128 + (kb ^ ((brow & 7) << 4)));
#pragma unroll
        for (int m = 0; m < 4; ++m)
          acc[m][n] = __builtin_amdgcn_mfma_f32_16x16x32_bf16(a[m], bfr, acc[m][n], 0, 0, 0);
      }
    }
    __syncthreads();
  }

  // epilogue: add linear bias, BiasNorm over the full 512-wide row
  const float escale = expf(log_scale[0]);
  float bl[8], bb[8], wb[8];
#pragma unroll
  for (int n = 0; n < 8; ++n) {
    int col = wc * 128 + n * 16 + lr;
    bl[n] = b_lin[col];
    bb[n] = bn_bias[col];
    if (MODE == 1) wb[n] = W_blank[col];
  }

  float ps[4][4];
#pragma unroll
  for (int m = 0; m < 4; ++m)
#pragma unroll
    for (int r = 0; r < 4; ++r) ps[m][r] = 0.f;
#pragma unroll
  for (int m = 0; m < 4; ++m)
#pragma unroll
    for (int n = 0; n < 8; ++n)
#pragma unroll
      for (int r = 0; r < 4; ++r) {
        float v = acc[m][n][r] + bl[n];
        float d = v - bb[n];
        ps[m][r] += d * d;
      }
#pragma unroll
  for (int off = 1; off < 16; off <<= 1)
#pragma unroll
    for (int m = 0; m < 4; ++m)
#pragma unroll
      for (int r = 0; r < 4; ++r)
        ps[m][r] += __shfl_xor(ps[m][r], off);

  if (lr == 0) {
#pragma unroll
    for (int m = 0; m < 4; ++m)
#pragma unroll
      for (int r = 0; r < 4; ++r)
        red[wc][wr * 64 + m * 16 + lq * 4 + r] = ps[m][r];
  }
  __syncthreads();
  if (tid < 128) {
    float s = red[0][tid] + red[1][tid] + red[2][tid] + red[3][tid];
    scale_s[tid] = escale * rsqrtf(s * (1.0f / 512.0f));
  }
  __syncthreads();

  if (MODE == 0) {
#pragma unroll
    for (int m = 0; m < 4; ++m)
#pragma unroll
      for (int n = 0; n < 8; ++n)
#pragma unroll
        for (int r = 0; r < 4; ++r) {
          int rl = wr * 64 + m * 16 + lq * 4 + r;
          int col = wc * 128 + n * 16 + lr;
          float v = (acc[m][n][r] + bl[n]) * scale_s[rl];
          enc_b[(long long)(rowBase + rl) * 512 + col] = f2bf(v);
        }
  } else {
    float pb[4][4];
#pragma unroll
    for (int m = 0; m < 4; ++m)
#pragma unroll
      for (int r = 0; r < 4; ++r) pb[m][r] = 0.f;
#pragma unroll
    for (int m = 0; m < 4; ++m)
#pragma unroll
      for (int n = 0; n < 8; ++n)
#pragma unroll
        for (int r = 0; r < 4; ++r) {
          int rl = wr * 64 + m * 16 + lq * 4 + r;
          int col = wc * 128 + n * 16 + lr;
          float v = (acc[m][n][r] + bl[n]) * scale_s[rl];
          float e = bf2f(enc_b[(long long)(rowBase + rl) * 512 + col]);
          float s = e + v;
          s = s > 0.f ? s : 0.f;
          pb[m][r] += s * wb[n];
        }
#pragma unroll
    for (int off = 1; off < 16; off <<= 1)
#pragma unroll
      for (int m = 0; m < 4; ++m)
#pragma unroll
        for (int r = 0; r < 4; ++r)
          pb[m][r] += __shfl_xor(pb[m][r], off);
    if (lr == 0) {
#pragma unroll
      for (int m = 0; m < 4; ++m)
#pragma unroll
        for (int r = 0; r < 4; ++r)
          red[wc][wr * 64 + m * 16 + lq * 4 + r] = pb[m][r];
    }
    __syncthreads();
    if (tid < 128)
      outp[(long long)(rowBase + tid) * 2000] =
          red[0][tid] + red[1][tid] + red[2][tid] + red[3][tid] + b_blank[0];
  }
}

// ---- BiasNorm of vocab_decoder_out (one wave per row) ----
__global__ __launch_bounds__(256)
void vdec_norm_kernel(const float* __restrict__ X, const float* __restrict__ bn_bias,
                      const float* __restrict__ log_scale, unsigned short* __restrict__ dst)
{
  const int l = threadIdx.x & 63;
  const long long row = (long long)blockIdx.x * 4 + (threadIdx.x >> 6);
  const float* xr = X + row * 512 + l * 8;
  float4 v0 = *(const float4*)xr;
  float4 v1 = *(const float4*)(xr + 4);
  float xv[8] = {v0.x, v0.y, v0.z, v0.w, v1.x, v1.y, v1.z, v1.w};
  const float4 b0 = *(const float4*)(bn_bias + l * 8);
  const float4 b1 = *(const float4*)(bn_bias + l * 8 + 4);
  float bv[8] = {b0.x, b0.y, b0.z, b0.w, b1.x, b1.y, b1.z, b1.w};
  float s = 0.f;
#pragma unroll
  for (int i = 0; i < 8; ++i) { float d = xv[i] - bv[i]; s += d * d; }
#pragma unroll
  for (int off = 1; off < 64; off <<= 1) s += __shfl_xor(s, off);
  const float sc = expf(log_scale[0]) * rsqrtf(s * (1.0f / 512.0f));
  bh8 o;
#pragma unroll
  for (int i = 0; i < 8; ++i) o[i] = (short)f2bf(xv[i] * sc);
  *(bh8*)(dst + row * 512 + l * 8) = o;
}

// ---- 128x128 GEMM vs (padded) 2048x512 bf16 weights ----
// MODE 0: dstf[r*1999 + col] = acc + bias[col]           (raw logits into vdp region)
// MODE 1: dstf[r*2000 + 1 + col] = acc + bias[col] + vdp[r*1999 + col]
template<int MODE>
__global__ __launch_bounds__(256, 2)
void gemm_out_kernel(const unsigned short* __restrict__ Abf,
                     const unsigned short* __restrict__ Wb,
                     const float* __restrict__ bias,
                     const float* __restrict__ vdp,
                     float* __restrict__ dstf)
{
  __shared__ unsigned short As[128 * 64];
  __shared__ unsigned short Bs[128 * 64];
  const int tid = threadIdx.x;
  const int l  = tid & 63, lq = l >> 4, lr = l & 15;
  const int w  = tid >> 6;
  const int wr = w >> 1, wc = w & 1;
  const int rowBase = blockIdx.x * 128;
  const int colBase = blockIdx.y * 128;
  char* AsB = (char*)As;
  char* BsB = (char*)Bs;

  fx4 acc[4][4];
#pragma unroll
  for (int m = 0; m < 4; ++m)
#pragma unroll
    for (int n = 0; n < 4; ++n)
#pragma unroll
      for (int r = 0; r < 4; ++r) acc[m][n][r] = 0.f;

  for (int kt = 0; kt < 8; ++kt) {
#pragma unroll
    for (int p = 0; p < 4; ++p) {
      int gb = (w * 4 + p) * 64;
      int g = gb + l;
      int row = g >> 3;
      int c8 = (g & 7) ^ (row & 7);
      gload_lds16(Abf + (long long)(rowBase + row) * 512 + kt * 64 + c8 * 8, AsB + gb * 16);
      gload_lds16(Wb  + (long long)(colBase + row) * 512 + kt * 64 + c8 * 8, BsB + gb * 16);
    }
    __syncthreads();
#pragma unroll
    for (int kk = 0; kk < 2; ++kk) {
      const int kb = (kk * 32 + lq * 8) * 2;
      bh8 a[4];
#pragma unroll
      for (int m = 0; m < 4; ++m) {
        int row = wr * 64 + m * 16 + lr;
        a[m] = *(const bh8*)(AsB + row * 128 + (kb ^ ((row & 7) << 4)));
      }
#pragma unroll
      for (int n = 0; n < 4; ++n) {
        int brow = wc * 64 + n * 16 + lr;
        bh8 bfr = *(const bh8*)(BsB + brow * 128 + (kb ^ ((brow & 7) << 4)));
#pragma unroll
        for (int m = 0; m < 4; ++m)
          acc[m][n] = __builtin_amdgcn_mfma_f32_16x16x32_bf16(a[m], bfr, acc[m][n], 0, 0, 0);
      }
    }
    __syncthreads();
  }

#pragma unroll
  for (int n = 0; n < 4; ++n) {
    int col = colBase + wc * 64 + n * 16 + lr;
    if (col < OV) {
      float bc = bias[col];
#pragma unroll
      for (int m = 0; m < 4; ++m)
#pragma unroll
        for (int r = 0; r < 4; ++r) {
          long long rg = rowBase + wr * 64 + m * 16 + lq * 4 + r;
          float v = acc[m][n][r] + bc;
          if (MODE == 0) dstf[rg * OV + col] = v;
          else           dstf[rg * 2000 + 1 + col] = v + vdp[rg * OV + col];
        }
    }
  }
}

// ---- in-place row log-softmax over 1999 cols ----
__global__ __launch_bounds__(256)
void lsm_kernel(float* __restrict__ vdp)
{
  const long long r = blockIdx.x;
  float* row = vdp + r * OV;
  const int t = threadIdx.x;
  const int w = t >> 6;
  __shared__ float sm[4], ss[4];
  float v[8];
  float mx = -3.4e38f;
#pragma unroll
  for (int i = 0; i < 8; ++i) {
    int idx = i * 256 + t;
    v[i] = (idx < OV) ? row[idx] : -3.4e38f;
    mx = fmaxf(mx, v[i]);
  }
#pragma unroll
  for (int off = 1; off < 64; off <<= 1) mx = fmaxf(mx, __shfl_xor(mx, off));
  if ((t & 63) == 0) sm[w] = mx;
  __syncthreads();
  mx = fmaxf(fmaxf(sm[0], sm[1]), fmaxf(sm[2], sm[3]));
  float s = 0.f;
#pragma unroll
  for (int i = 0; i < 8; ++i) s += expf(v[i] - mx);
  ;
#pragma unroll
  for (int off = 1; off < 64; off <<= 1) s += __shfl_xor(s, off);
  if ((t & 63) == 0) ss[w] = s;
  __syncthreads();
  s = ss[0] + ss[1] + ss[2] + ss[3];
  const float lz = mx + logf(s);
#pragma unroll
  for (int i = 0; i < 8; ++i) {
    int idx = i * 256 + t;
    if (idx < OV) row[idx] = v[i] - lz;
  }
}

extern "C" void kernel_launch(void* const* d_in, const int* in_sizes, int n_in,
                              void* d_out, int out_size, void* d_ws, size_t ws_size,
                              hipStream_t stream) {
  const float* encoder_out  = (const float*)d_in[0];
  const float* blank_dec    = (const float*)d_in[1];
  const float* vocab_dec    = (const float*)d_in[2];
  const float* W_enc        = (const float*)d_in[3];
  const float* b_enc        = (const float*)d_in[4];
  const float* bn_enc_bias  = (const float*)d_in[5];
  const float* bn_enc_ls    = (const float*)d_in[6];
  const float* W_bdec       = (const float*)d_in[7];
  const float* b_bdec       = (const float*)d_in[8];
  const float* bn_bdec_bias = (const float*)d_in[9];
  const float* bn_bdec_ls   = (const float*)d_in[10];
  const float* bn_vdec_bias = (const float*)d_in[11];
  const float* bn_vdec_ls   = (const float*)d_in[12];
  const float* W_blank      = (const float*)d_in[13];
  const float* b_blank      = (const float*)d_in[14];
  const float* W_ev         = (const float*)d_in[15];
  const float* b_ev         = (const float*)d_in[16];
  const float* W_dv         = (const float*)d_in[17];
  const float* b_dv         = (const float*)d_in[18];

  unsigned short* Wenc_b  = (unsigned short*)d_ws;                 // 512x512
  unsigned short* Wbdec_b = Wenc_b + 512 * 512;                    // 512x512
  unsigned short* Wdv_b   = Wbdec_b + 512 * 512;                   // 2048x512 (rows >=1999 zero)
  unsigned short* Wev_b   = Wdv_b + 2048 * 512;                    // 2048x512
  unsigned short* enc_b   = Wev_b + 2048 * 512;                    // R x 512
  unsigned short* vdec_b  = enc_b + (size_t)R_TOTAL * 512;         // R x 512

  float* outp = (float*)d_out;                  // R x 2000
  float* vdp  = outp + (size_t)R_TOTAL * 2000;  // R x 1999

  wconv_kernel<<<256, 256, 0, stream>>>(W_enc,  Wenc_b,  512, 512);
  wconv_kernel<<<256, 256, 0, stream>>>(W_bdec, Wbdec_b, 512, 512);
  wconv_kernel<<<512, 256, 0, stream>>>(W_dv,   Wdv_b,  1999, 2048);
  wconv_kernel<<<512, 256, 0, stream>>>(W_ev,   Wev_b,  1999, 2048);

  proj_norm_kernel<0><<<250, 512, 0, stream>>>(encoder_out, Wenc_b, b_enc, bn_enc_bias,
                                               bn_enc_ls, enc_b, nullptr, nullptr, nullptr);
  proj_norm_kernel<1><<<250, 512, 0, stream>>>(blank_dec, Wbdec_b, b_bdec, bn_bdec_bias,
                                               bn_bdec_ls, enc_b, W_blank, b_blank, outp);
  vdec_norm_kernel<<<8000, 256, 0, stream>>>(vocab_dec, bn_vdec_bias, bn_vdec_ls, vdec_b);

  gemm_out_kernel<0><<<dim3(250, 16), 256, 0, stream>>>(vdec_b, Wdv_b, b_dv, nullptr, vdp);
  lsm_kernel<<<32000, 256, 0, stream>>>(vdp);
  gemm_out_kernel<1><<<dim3(250, 16), 256, 0, stream>>>(enc_b, Wev_b, b_ev, vdp, outp);
}